// Round 11
// baseline (5252.067 us; speedup 1.0000x reference)
//
#include <hip/hip_runtime.h>
#include <hip/hip_fp16.h>

#define BB 8
#define SS 2048
#define EE 1024
#define NHH 4
#define DHH 256

typedef _Float16 f16x2 __attribute__((ext_vector_type(2)));
typedef _Float16 f16x8 __attribute__((ext_vector_type(8)));
typedef float f32x4 __attribute__((ext_vector_type(4)));

__device__ __forceinline__ __half2 u2h2(unsigned int u) {
  union { unsigned int u; __half2 h; } c; c.u = u; return c.h;
}
__device__ __forceinline__ unsigned int h2u(__half2 h) {
  union { unsigned int u; __half2 h; } c; c.h = h; return c.u;
}
__device__ __forceinline__ f16x2 u2f(unsigned int u) {
  union { unsigned int u; f16x2 f; } c; c.u = u; return c.f;
}
__device__ __forceinline__ unsigned int pack2(float a, float b) {
  f16x2 f; f.x = (_Float16)a; f.y = (_Float16)b;
  union { f16x2 f; unsigned int u; } c; c.f = f; return c.u;
}
__device__ __forceinline__ float fdot2u(unsigned int w, unsigned int y, float acc) {
#if __has_builtin(__builtin_amdgcn_fdot2)
  return __builtin_amdgcn_fdot2(u2f(w), u2f(y), acc, false);
#else
  __half2 a = u2h2(w), b = u2h2(y);
  return acc + __low2float(a) * __low2float(b) + __high2float(a) * __high2float(b);
#endif
}

// ---------------------------------------------------------------------------
// Gates projection GEMM via MFMA f16 (round-10 verbatim, verified).
// Output: gx f16, layout [S][B][NH][4*DH] = [i f z o]
// ---------------------------------------------------------------------------
__global__ __launch_bounds__(256) void gates_gemm(
    const float* __restrict__ x, const float* __restrict__ conv_w,
    const float* __restrict__ conv_b,
    const float* __restrict__ fgw, const float* __restrict__ igw,
    const float* __restrict__ zgw, const float* __restrict__ ogw,
    __half* __restrict__ gx)
{
  __shared__ float Xs[8][11][33];
  __shared__ __half As[64][40];
  __shared__ __half Bs[64][40];

  const int tid = threadIdx.x;
  const int mt = blockIdx.x;
  const int nt = blockIdx.y;
  const int p  = blockIdx.z;
  const int h  = p >> 1, pair = p & 1;
  const int s0 = mt << 3;
  const int n0 = nt << 6;

  const float* W0 = pair ? zgw : fgw;
  const float* W1 = pair ? ogw : igw;

  const int w = tid >> 6, l = tid & 63;
  const int lrow = l & 15, kq = l >> 4;
  const int koff = kq << 3;

  f32x4 acc[4] = {};

  for (int d0 = 0; d0 < DHH; d0 += 32) {
    const int ebase = h * DHH + d0;

    if (pair == 0) {
      for (int i = tid; i < 8 * 11 * 32; i += 256) {
        int kk = i & 31, rest = i >> 5;
        int b = rest / 11, si = rest - b * 11;
        int sg = s0 - 3 + si;
        float v = 0.f;
        if (sg >= 0) v = x[((size_t)b * SS + sg) * EE + ebase + kk];
        Xs[b][si][kk] = v;
      }
      __syncthreads();
      for (int i = tid; i < 64 * 32; i += 256) {
        int kk = i & 31, r = i >> 5;
        int sl = r >> 3, b = r & 7;
        int e = ebase + kk;
        float xc = conv_b[e];
        xc = fmaf(Xs[b][sl + 0][kk], conv_w[0 * EE + e], xc);
        xc = fmaf(Xs[b][sl + 1][kk], conv_w[1 * EE + e], xc);
        xc = fmaf(Xs[b][sl + 2][kk], conv_w[2 * EE + e], xc);
        xc = fmaf(Xs[b][sl + 3][kk], conv_w[3 * EE + e], xc);
        float sg = 1.f / (1.f + __expf(-xc));
        As[r][kk] = __float2half(xc * sg);
      }
    } else {
      for (int i = tid; i < 64 * 32; i += 256) {
        int kk = i & 31, r = i >> 5;
        int sl = r >> 3, b = r & 7;
        As[r][kk] = __float2half(x[((size_t)b * SS + s0 + sl) * EE + ebase + kk]);
      }
    }
    for (int i = tid; i < 64 * 32; i += 256) {
      int k = i & 31, col = i >> 5;
      int o = n0 + col;
      const float* Wp = (o < 256) ? W0 : W1;
      int oo = o & 255;
      Bs[col][k] = __float2half(Wp[((size_t)h * DHH + oo) * DHH + d0 + k]);
    }
    __syncthreads();

    f16x8 bfrag = *(const f16x8*)&Bs[w * 16 + lrow][koff];
#pragma unroll
    for (int mtl = 0; mtl < 4; ++mtl) {
      f16x8 afrag = *(const f16x8*)&As[mtl * 16 + lrow][koff];
      acc[mtl] = __builtin_amdgcn_mfma_f32_16x16x32_f16(afrag, bfrag, acc[mtl], 0, 0, 0);
    }
    __syncthreads();
  }

#pragma unroll
  for (int mtl = 0; mtl < 4; ++mtl) {
#pragma unroll
    for (int j = 0; j < 4; ++j) {
      int row_loc = mtl * 16 + kq * 4 + j;
      int grow = s0 * 8 + row_loc;
      int colg = n0 + w * 16 + lrow;
      gx[(size_t)grow * 4096 + h * 1024 + pair * 512 + colg] = __float2half(acc[mtl][j]);
    }
  }
}

// ---------------------------------------------------------------------------
// sLSTM scan v3: one WG of 1024 threads per chain (b,h); 1 WG/CU.
// Thread t -> (dim d = t>>2, gate g = t&3) owns ONE full column
// col = g*256+d (k = 0..255): 128 half2 = 92 in arch VGPRs + 36 in LDS
// (9 uint4 per thread, [9][1024] = 147456 B). At 1024 thr the per-thread
// weight load halves vs the 512-thr design -> fits the 128-reg budget with
// NO AGPR move tax (the measured 2x VALU inflation of rounds 3-6).
// __launch_bounds__(1024,4): 4 waves/EU = 16 waves/CU = 1 WG -> 128-reg cap.
// y: [2][256] f16 double-buffered in LDS; reads are pure wave-broadcast.
// Gate gather: 3 shfl_xor in the 4-lane group (round-7-verified mapping).
// One barrier per step. Dynamic LDS: 147456 + 1024 = 148480 B.
// ---------------------------------------------------------------------------
__global__ __launch_bounds__(1024, 4)
void slstm_scan3(
    const float* __restrict__ rk,    // (NH, DH, 4*DH)
    const float* __restrict__ rb,    // (NH, 4, DH)
    const __half* __restrict__ gx,   // [S][B][NH][1024]
    float* __restrict__ out)         // (B, S, E)
{
  extern __shared__ unsigned char smem[];
  uint4* wlds  = (uint4*)smem;                      // [9][1024]
  __half* ypub = (__half*)(smem + 147456);          // [2][256]

  const int t = threadIdx.x;
  const int d = t >> 2, g = t & 3;
  const int b = blockIdx.x >> 2, h = blockIdx.x & 3;
  const int col = g * 256 + d;
  const float* Rh = rk + (size_t)h * DHH * 1024;

  // weights: half2 chunks 0..22 in regs (92 dwords), 23..31 in LDS (36)
  unsigned int wreg[92];
#pragma unroll
  for (int i = 0; i < 92; ++i)
    wreg[i] = pack2(Rh[(size_t)(2 * i) * 1024 + col],
                    Rh[(size_t)(2 * i + 1) * 1024 + col]);
  for (int q = 0; q < 9; ++q) {
    int kk = 184 + 8 * q;
    uint4 u;
    u.x = pack2(Rh[(size_t)(kk + 0) * 1024 + col], Rh[(size_t)(kk + 1) * 1024 + col]);
    u.y = pack2(Rh[(size_t)(kk + 2) * 1024 + col], Rh[(size_t)(kk + 3) * 1024 + col]);
    u.z = pack2(Rh[(size_t)(kk + 4) * 1024 + col], Rh[(size_t)(kk + 5) * 1024 + col]);
    u.w = pack2(Rh[(size_t)(kk + 6) * 1024 + col], Rh[(size_t)(kk + 7) * 1024 + col]);
    wlds[q * 1024 + t] = u;
  }
  const float rbv = rb[h * 1024 + col];

  float cst = 0.f, nst = 0.f, mst = 0.f;
  if (t < 256) { ypub[t] = __float2half(0.f); ypub[256 + t] = __float2half(0.f); }
  __syncthreads();

  int cur = 0;
  const __half* gp = gx + ((size_t)b * NHH + h) * 1024 + col;
  const size_t gxstep = (size_t)BB * NHH * 1024;
  const size_t outb = ((size_t)b * SS) * EE + h * DHH + d;

  for (int st = 0; st < SS; ++st) {
    const float cx = __half2float(gp[(size_t)st * gxstep]);  // issued early

    const uint4* yv = (const uint4*)(ypub + cur * 256);
    float acc = 0.f;
#pragma unroll
    for (int j = 0; j < 23; ++j) {       // k-chunks from registers
      uint4 yq = yv[j];
      acc = fdot2u(wreg[4 * j + 0], yq.x, acc);
      acc = fdot2u(wreg[4 * j + 1], yq.y, acc);
      acc = fdot2u(wreg[4 * j + 2], yq.z, acc);
      acc = fdot2u(wreg[4 * j + 3], yq.w, acc);
    }
#pragma unroll
    for (int q = 0; q < 9; ++q) {        // k-chunks from LDS
      uint4 yq = yv[23 + q];
      uint4 wq = wlds[q * 1024 + t];
      acc = fdot2u(wq.x, yq.x, acc);
      acc = fdot2u(wq.y, yq.y, acc);
      acc = fdot2u(wq.z, yq.z, acc);
      acc = fdot2u(wq.w, yq.w, acc);
    }

    float v0 = acc + cx + rbv;           // complete raw gate g at dim d

    // gather all 4 gates within the 4-lane group (verified mapping)
    float x1 = __shfl_xor(v0, 1);
    float x2 = __shfl_xor(v0, 2);
    float x3 = __shfl_xor(x1, 2);
    float iv = (g == 0) ? v0 : (g == 1) ? x1 : (g == 2) ? x2 : x3;
    float fv = (g == 0) ? x1 : (g == 1) ? v0 : (g == 2) ? x3 : x2;
    float zv = (g == 0) ? x2 : (g == 1) ? x3 : (g == 2) ? v0 : x1;
    float ov = (g == 0) ? x3 : (g == 1) ? x2 : (g == 2) ? x1 : v0;

    // state update (redundant across the 4 lanes of a dim)
    float ea = __expf(-fabsf(fv));
    float ls = fminf(fv, 0.f) - __logf(1.f + ea);      // log_sigmoid(fv)
    float lfm = mst + ls;
    float mn = fmaxf(iv, lfm);
    float ig = __expf(iv - mn);
    float fg = __expf(lfm - mn);
    float pz = __expf(-2.f * fabsf(zv));
    float tmag = __fdividef(1.f - pz, 1.f + pz);
    float th = (zv < 0.f) ? -tmag : tmag;              // tanh(zv)
    cst = fg * cst + ig * th;
    nst = fg * nst + ig;
    float og = __fdividef(1.f, 1.f + __expf(-ov));     // sigmoid(ov)
    float y = og * __fdividef(cst, nst);
    mst = mn;

    if (g == 0) {
      out[outb + (size_t)st * EE] = y;
      ypub[(cur ^ 1) * 256 + d] = __float2half(y);
    }
    __syncthreads();
    cur ^= 1;
  }
}

// ---------------------------------------------------------------------------
// GroupNorm over DH per (b,s,h), in place on out. One wave = one head.
// ---------------------------------------------------------------------------
__global__ __launch_bounds__(256) void groupnorm(
    float* __restrict__ y, const float* __restrict__ gnw)
{
  const int row = blockIdx.x;
  const int t = threadIdx.x;
  float4 v = ((const float4*)y)[(size_t)row * 256 + t];
  float s = v.x + v.y + v.z + v.w;
  float q = v.x * v.x + v.y * v.y + v.z * v.z + v.w * v.w;
#pragma unroll
  for (int mask = 1; mask < 64; mask <<= 1) {
    s += __shfl_xor(s, mask, 64);
    q += __shfl_xor(q, mask, 64);
  }
  float mu = s * (1.f / 256.f);
  float var = q * (1.f / 256.f) - mu * mu;
  float rs = rsqrtf(var + 1e-5f);
  float4 g = ((const float4*)gnw)[t];
  float4 o;
  o.x = (v.x - mu) * rs * g.x;
  o.y = (v.y - mu) * rs * g.y;
  o.z = (v.z - mu) * rs * g.z;
  o.w = (v.w - mu) * rs * g.w;
  ((float4*)y)[(size_t)row * 256 + t] = o;
}

extern "C" void kernel_launch(void* const* d_in, const int* in_sizes, int n_in,
                              void* d_out, int out_size, void* d_ws, size_t ws_size,
                              hipStream_t stream) {
  const float* x      = (const float*)d_in[0];
  const float* conv_w = (const float*)d_in[1];
  const float* conv_b = (const float*)d_in[2];
  const float* fgw    = (const float*)d_in[3];
  const float* igw    = (const float*)d_in[4];
  const float* zgw    = (const float*)d_in[5];
  const float* ogw    = (const float*)d_in[6];
  const float* rk     = (const float*)d_in[7];
  const float* rb     = (const float*)d_in[8];
  const float* gnw    = (const float*)d_in[9];
  float* out = (float*)d_out;
  __half* gx = (__half*)d_ws;   // [S][B][NH][1024] f16 = 134217728 B

  dim3 g1(256, 8, 8);
  gates_gemm<<<g1, 256, 0, stream>>>(x, conv_w, conv_b, fgw, igw, zgw, ogw, gx);

  const int scan_lds = 147456 + 1024;
  (void)hipFuncSetAttribute(reinterpret_cast<const void*>(slstm_scan3),
                            hipFuncAttributeMaxDynamicSharedMemorySize, scan_lds);
  slstm_scan3<<<32, 1024, scan_lds, stream>>>(rk, rb, gx, out);

  groupnorm<<<BB * SS, 256, 0, stream>>>(out, gnw);
}

// Round 12
// 4347.942 us; speedup vs baseline: 1.2079x; 1.2079x over previous
//
#include <hip/hip_runtime.h>
#include <hip/hip_fp16.h>

#define BB 8
#define SS 2048
#define EE 1024
#define NHH 4
#define DHH 256

typedef _Float16 f16x2 __attribute__((ext_vector_type(2)));
typedef _Float16 f16x8 __attribute__((ext_vector_type(8)));
typedef float f32x4 __attribute__((ext_vector_type(4)));

__device__ __forceinline__ __half2 u2h2(unsigned int u) {
  union { unsigned int u; __half2 h; } c; c.u = u; return c.h;
}
__device__ __forceinline__ unsigned int h2u(__half2 h) {
  union { unsigned int u; __half2 h; } c; c.h = h; return c.u;
}

// ---------------------------------------------------------------------------
// Gates projection GEMM via MFMA f16 (round-10 verbatim, verified).
// Output: gx f16, layout [S][B][NH][4*DH] = [i f z o]
// ---------------------------------------------------------------------------
__global__ __launch_bounds__(256) void gates_gemm(
    const float* __restrict__ x, const float* __restrict__ conv_w,
    const float* __restrict__ conv_b,
    const float* __restrict__ fgw, const float* __restrict__ igw,
    const float* __restrict__ zgw, const float* __restrict__ ogw,
    __half* __restrict__ gx)
{
  __shared__ float Xs[8][11][33];
  __shared__ __half As[64][40];
  __shared__ __half Bs[64][40];

  const int tid = threadIdx.x;
  const int mt = blockIdx.x;
  const int nt = blockIdx.y;
  const int p  = blockIdx.z;
  const int h  = p >> 1, pair = p & 1;
  const int s0 = mt << 3;
  const int n0 = nt << 6;

  const float* W0 = pair ? zgw : fgw;
  const float* W1 = pair ? ogw : igw;

  const int w = tid >> 6, l = tid & 63;
  const int lrow = l & 15, kq = l >> 4;
  const int koff = kq << 3;

  f32x4 acc[4] = {};

  for (int d0 = 0; d0 < DHH; d0 += 32) {
    const int ebase = h * DHH + d0;

    if (pair == 0) {
      for (int i = tid; i < 8 * 11 * 32; i += 256) {
        int kk = i & 31, rest = i >> 5;
        int b = rest / 11, si = rest - b * 11;
        int sg = s0 - 3 + si;
        float v = 0.f;
        if (sg >= 0) v = x[((size_t)b * SS + sg) * EE + ebase + kk];
        Xs[b][si][kk] = v;
      }
      __syncthreads();
      for (int i = tid; i < 64 * 32; i += 256) {
        int kk = i & 31, r = i >> 5;
        int sl = r >> 3, b = r & 7;
        int e = ebase + kk;
        float xc = conv_b[e];
        xc = fmaf(Xs[b][sl + 0][kk], conv_w[0 * EE + e], xc);
        xc = fmaf(Xs[b][sl + 1][kk], conv_w[1 * EE + e], xc);
        xc = fmaf(Xs[b][sl + 2][kk], conv_w[2 * EE + e], xc);
        xc = fmaf(Xs[b][sl + 3][kk], conv_w[3 * EE + e], xc);
        float sg = 1.f / (1.f + __expf(-xc));
        As[r][kk] = __float2half(xc * sg);
      }
    } else {
      for (int i = tid; i < 64 * 32; i += 256) {
        int kk = i & 31, r = i >> 5;
        int sl = r >> 3, b = r & 7;
        As[r][kk] = __float2half(x[((size_t)b * SS + s0 + sl) * EE + ebase + kk]);
      }
    }
    for (int i = tid; i < 64 * 32; i += 256) {
      int k = i & 31, col = i >> 5;
      int o = n0 + col;
      const float* Wp = (o < 256) ? W0 : W1;
      int oo = o & 255;
      Bs[col][k] = __float2half(Wp[((size_t)h * DHH + oo) * DHH + d0 + k]);
    }
    __syncthreads();

    f16x8 bfrag = *(const f16x8*)&Bs[w * 16 + lrow][koff];
#pragma unroll
    for (int mtl = 0; mtl < 4; ++mtl) {
      f16x8 afrag = *(const f16x8*)&As[mtl * 16 + lrow][koff];
      acc[mtl] = __builtin_amdgcn_mfma_f32_16x16x32_f16(afrag, bfrag, acc[mtl], 0, 0, 0);
    }
    __syncthreads();
  }

#pragma unroll
  for (int mtl = 0; mtl < 4; ++mtl) {
#pragma unroll
    for (int j = 0; j < 4; ++j) {
      int row_loc = mtl * 16 + kq * 4 + j;
      int grow = s0 * 8 + row_loc;
      int colg = n0 + w * 16 + lrow;
      gx[(size_t)grow * 4096 + h * 1024 + pair * 512 + colg] = __float2half(acc[mtl][j]);
    }
  }
}

// ---------------------------------------------------------------------------
// sLSTM scan v4: MFMA matvec. One WG (512 thr, 8 waves) per chain (b,h).
// Wave w owns cols [w*128, w*128+128) = 8 N-tiles of 16 cols.
//   N-tiles 0..5: B-fragments in registers (192 dwords/lane -> AGPR, consumed
//                 DIRECTLY by v_mfma: no accvgpr move tax, the round-3..11 killer)
//   N-tiles 6..7: B-fragments streamed from LDS in fragment order
//                 (consecutive-lane b128, conflict-free).
// A-operand: y(st) broadcast, M=1 of 16 rows used (lanes l%16==0 read 16B of
// ypub, rest zero). mfma_f32_16x16x32_f16 layouts HW-verified by gates_gemm.
// Epilogue: row-0 results live in lanes 0..15 reg 0 -> raw[1024] f32 in LDS;
// 256 state threads do gates->state->y; 2 barriers/step.
// Dynamic LDS: 131072 (ldsB) + 1024 (ypub) + 4096 (raw) = 136192 B (1 WG/CU).
// ---------------------------------------------------------------------------
__global__ __launch_bounds__(512)
void slstm_scan4(
    const float* __restrict__ rk,    // (NH, DH, 4*DH)
    const float* __restrict__ rb,    // (NH, 4, DH)
    const __half* __restrict__ gx,   // [S][B][NH][1024]
    float* __restrict__ out)         // (B, S, E)
{
  extern __shared__ unsigned char smem[];
  uint4* ldsB  = (uint4*)smem;                 // [8w][2nt][8kt][64l] = 131072 B
  __half* ypub = (__half*)(smem + 131072);     // [2][256]
  float* rawb  = (float*)(smem + 132096);      // [1024]

  const int t = threadIdx.x;
  const int w = t >> 6, l = t & 63;
  const int lrow = l & 15, lkq = l >> 4;
  const int b = blockIdx.x >> 2, h = blockIdx.x & 3;
  const float* Rh = rk + (size_t)h * DHH * 1024;
  const int n0w = w << 7;

  // B-fragments for N-tiles 0..5 into registers (-> AGPR)
  f16x8 wB[6][8];
#pragma unroll
  for (int nt = 0; nt < 6; ++nt) {
    const int col = n0w + nt * 16 + lrow;
#pragma unroll
    for (int kt = 0; kt < 8; ++kt) {
      f16x8 f;
#pragma unroll
      for (int i = 0; i < 4; ++i) {
        const int k = kt * 32 + lkq * 8 + 2 * i;
        f[2 * i]     = (_Float16)Rh[(size_t)k * 1024 + col];
        f[2 * i + 1] = (_Float16)Rh[(size_t)(k + 1) * 1024 + col];
      }
      wB[nt][kt] = f;
    }
  }
  // B-fragments for N-tiles 6..7 into LDS, fragment order
  for (int j = 0; j < 2; ++j) {
    const int col = n0w + (6 + j) * 16 + lrow;
    for (int kt = 0; kt < 8; ++kt) {
      f16x8 f;
      for (int i = 0; i < 4; ++i) {
        const int k = kt * 32 + lkq * 8 + 2 * i;
        f[2 * i]     = (_Float16)Rh[(size_t)k * 1024 + col];
        f[2 * i + 1] = (_Float16)Rh[(size_t)(k + 1) * 1024 + col];
      }
      *(f16x8*)&ldsB[((w * 2 + j) * 8 + kt) * 64 + l] = f;
    }
  }

  // state-thread setup (t < 256: owns dim d = t)
  const int d = t & 255;
  float rb0 = 0.f, rb1 = 0.f, rb2 = 0.f, rb3 = 0.f;
  if (t < 256) {
    rb0 = rb[h * 1024 + d];
    rb1 = rb[h * 1024 + 256 + d];
    rb2 = rb[h * 1024 + 512 + d];
    rb3 = rb[h * 1024 + 768 + d];
    ypub[d] = __float2half(0.f);
    ypub[256 + d] = __float2half(0.f);
  }
  __syncthreads();

  float cst = 0.f, nst = 0.f, mst = 0.f;
  const size_t gxstep = (size_t)BB * NHH * 1024;
  const __half* gp = gx + ((size_t)b * NHH + h) * 1024;
  float cx0 = 0.f, cx1 = 0.f, cx2 = 0.f, cx3 = 0.f;
  if (t < 256) {
    cx0 = __half2float(gp[d]);
    cx1 = __half2float(gp[256 + d]);
    cx2 = __half2float(gp[512 + d]);
    cx3 = __half2float(gp[768 + d]);
  }

  int cur = 0;
  for (int st = 0; st < SS; ++st) {
    // prefetch next step's gate inputs (hidden under MFMA)
    __half nx0, nx1, nx2, nx3;
    if (t < 256) {
      const __half* pn = gp + (size_t)((st + 1 < SS) ? st + 1 : st) * gxstep;
      nx0 = pn[d]; nx1 = pn[256 + d]; nx2 = pn[512 + d]; nx3 = pn[768 + d];
    }

    const __half* yc = ypub + cur * 256;
    f32x4 a0 = {}, a1 = {}, a2 = {}, a3 = {}, a4 = {}, a5 = {}, a6 = {}, a7 = {};
#pragma unroll
    for (int kt = 0; kt < 8; ++kt) {
      f16x8 A = {};
      if (lrow == 0) A = *(const f16x8*)(yc + kt * 32 + lkq * 8);
      a0 = __builtin_amdgcn_mfma_f32_16x16x32_f16(A, wB[0][kt], a0, 0, 0, 0);
      a1 = __builtin_amdgcn_mfma_f32_16x16x32_f16(A, wB[1][kt], a1, 0, 0, 0);
      a2 = __builtin_amdgcn_mfma_f32_16x16x32_f16(A, wB[2][kt], a2, 0, 0, 0);
      a3 = __builtin_amdgcn_mfma_f32_16x16x32_f16(A, wB[3][kt], a3, 0, 0, 0);
      a4 = __builtin_amdgcn_mfma_f32_16x16x32_f16(A, wB[4][kt], a4, 0, 0, 0);
      a5 = __builtin_amdgcn_mfma_f32_16x16x32_f16(A, wB[5][kt], a5, 0, 0, 0);
      f16x8 b6 = *(const f16x8*)&ldsB[((w * 2 + 0) * 8 + kt) * 64 + l];
      f16x8 b7 = *(const f16x8*)&ldsB[((w * 2 + 1) * 8 + kt) * 64 + l];
      a6 = __builtin_amdgcn_mfma_f32_16x16x32_f16(A, b6, a6, 0, 0, 0);
      a7 = __builtin_amdgcn_mfma_f32_16x16x32_f16(A, b7, a7, 0, 0, 0);
    }
    // row-0 results: lanes 0..15, reg 0
    if (l < 16) {
      rawb[n0w +   0 + l] = a0[0];
      rawb[n0w +  16 + l] = a1[0];
      rawb[n0w +  32 + l] = a2[0];
      rawb[n0w +  48 + l] = a3[0];
      rawb[n0w +  64 + l] = a4[0];
      rawb[n0w +  80 + l] = a5[0];
      rawb[n0w +  96 + l] = a6[0];
      rawb[n0w + 112 + l] = a7[0];
    }
    __syncthreads();                       // b1: raw ready

    if (t < 256) {
      float iv = rawb[d]       + cx0 + rb0;
      float fv = rawb[256 + d] + cx1 + rb1;
      float zv = rawb[512 + d] + cx2 + rb2;
      float ov = rawb[768 + d] + cx3 + rb3;

      float ea = __expf(-fabsf(fv));
      float ls = fminf(fv, 0.f) - __logf(1.f + ea);    // log_sigmoid(fv)
      float lfm = mst + ls;
      float mn = fmaxf(iv, lfm);
      float ig = __expf(iv - mn);
      float fg = __expf(lfm - mn);
      float pz = __expf(-2.f * fabsf(zv));
      float tm = __fdividef(1.f - pz, 1.f + pz);
      float th = (zv < 0.f) ? -tm : tm;                // tanh(zv)
      cst = fg * cst + ig * th;
      nst = fg * nst + ig;
      float og = __fdividef(1.f, 1.f + __expf(-ov));   // sigmoid(ov)
      float y = og * __fdividef(cst, nst);
      mst = mn;

      out[((size_t)b * SS + st) * EE + h * DHH + d] = y;
      ypub[(cur ^ 1) * 256 + d] = __float2half(y);
    }
    __syncthreads();                       // b2: y ready
    cur ^= 1;
    cx0 = __half2float(nx0); cx1 = __half2float(nx1);
    cx2 = __half2float(nx2); cx3 = __half2float(nx3);
  }
}

// ---------------------------------------------------------------------------
// GroupNorm over DH per (b,s,h), in place on out. One wave = one head.
// ---------------------------------------------------------------------------
__global__ __launch_bounds__(256) void groupnorm(
    float* __restrict__ y, const float* __restrict__ gnw)
{
  const int row = blockIdx.x;
  const int t = threadIdx.x;
  float4 v = ((const float4*)y)[(size_t)row * 256 + t];
  float s = v.x + v.y + v.z + v.w;
  float q = v.x * v.x + v.y * v.y + v.z * v.z + v.w * v.w;
#pragma unroll
  for (int mask = 1; mask < 64; mask <<= 1) {
    s += __shfl_xor(s, mask, 64);
    q += __shfl_xor(q, mask, 64);
  }
  float mu = s * (1.f / 256.f);
  float var = q * (1.f / 256.f) - mu * mu;
  float rs = rsqrtf(var + 1e-5f);
  float4 g = ((const float4*)gnw)[t];
  float4 o;
  o.x = (v.x - mu) * rs * g.x;
  o.y = (v.y - mu) * rs * g.y;
  o.z = (v.z - mu) * rs * g.z;
  o.w = (v.w - mu) * rs * g.w;
  ((float4*)y)[(size_t)row * 256 + t] = o;
}

extern "C" void kernel_launch(void* const* d_in, const int* in_sizes, int n_in,
                              void* d_out, int out_size, void* d_ws, size_t ws_size,
                              hipStream_t stream) {
  const float* x      = (const float*)d_in[0];
  const float* conv_w = (const float*)d_in[1];
  const float* conv_b = (const float*)d_in[2];
  const float* fgw    = (const float*)d_in[3];
  const float* igw    = (const float*)d_in[4];
  const float* zgw    = (const float*)d_in[5];
  const float* ogw    = (const float*)d_in[6];
  const float* rk     = (const float*)d_in[7];
  const float* rb     = (const float*)d_in[8];
  const float* gnw    = (const float*)d_in[9];
  float* out = (float*)d_out;
  __half* gx = (__half*)d_ws;   // [S][B][NH][1024] f16 = 134217728 B

  dim3 g1(256, 8, 8);
  gates_gemm<<<g1, 256, 0, stream>>>(x, conv_w, conv_b, fgw, igw, zgw, ogw, gx);

  const int scan_lds = 131072 + 1024 + 4096;
  (void)hipFuncSetAttribute(reinterpret_cast<const void*>(slstm_scan4),
                            hipFuncAttributeMaxDynamicSharedMemorySize, scan_lds);
  slstm_scan4<<<32, 512, scan_lds, stream>>>(rk, rb, gx, out);

  groupnorm<<<BB * SS, 256, 0, stream>>>(out, gnw);
}